// Round 1
// baseline (1852.613 us; speedup 1.0000x reference)
//
#include <hip/hip_runtime.h>
#include <hip/hip_fp16.h>

#define NUSERS 60000
#define NITEMS 30000
#define NNODES 90000
#define KDIM 64
#define EH 1000000
#define E2 2000000
#define NBATCH 100000
#define EPSV 1e-8f

// ---------------- CSR build ----------------
__global__ void k_count(const int* __restrict__ edge_row, int* __restrict__ counts) {
    int e = blockIdx.x * 256 + threadIdx.x;
    if (e < E2) atomicAdd(&counts[edge_row[e]], 1);
}

// single-block scan over 90000 counts -> exclusive offsets (+ copy to cursor)
__global__ void k_scan(const int* __restrict__ counts, int* __restrict__ offsets,
                       int* __restrict__ cursor) {
    __shared__ int tmp[1024];
    int t = threadIdx.x;
    int carry = 0;
    for (int base = 0; base < NNODES; base += 1024) {
        int i = base + t;
        int v = (i < NNODES) ? counts[i] : 0;
        tmp[t] = v;
        __syncthreads();
        int acc = v;
        for (int o = 1; o < 1024; o <<= 1) {
            int add = (t >= o) ? tmp[t - o] : 0;
            __syncthreads();
            acc += add;
            tmp[t] = acc;
            __syncthreads();
        }
        int excl = carry + acc - v;
        if (i < NNODES) { offsets[i] = excl; cursor[i] = excl; }
        carry += tmp[1023];  // uniform read, valid after last barrier
        __syncthreads();     // protect tmp before next chunk overwrites
    }
    if (t == 0) offsets[NNODES] = carry;
}

__global__ void k_fill(const int* __restrict__ edge_row, const int* __restrict__ edge_col,
                       int* __restrict__ cursor, int2* __restrict__ csr) {
    int e = blockIdx.x * 256 + threadIdx.x;
    if (e >= E2) return;
    int r = edge_row[e];
    int slot = atomicAdd(&cursor[r], 1);
    csr[slot] = make_int2(edge_col[e], e);
}

// ---------------- q = (ef @ W + b)^2, fp16, for edge range [e0,e1) ----------------
__global__ void k_projq(const float* __restrict__ ef, const float* __restrict__ W,
                        const float* __restrict__ b, __half* __restrict__ q,
                        int e0, int e1) {
    __shared__ float Ws[64 * 64];
    __shared__ float bs[64];
    __shared__ float efs[16 * 72];  // stride 72: 16B-aligned rows, bank-spread
    int t = threadIdx.x;
    for (int i = t; i < 4096; i += 256) Ws[i] = W[i];
    if (t < 64) bs[t] = b[t];
    int le = t >> 4, kq = t & 15, k0 = kq * 4;
    int e = e0 + blockIdx.x * 16 + le;
    if (e < e1) {
        float4 efv = *(const float4*)&ef[(size_t)e * 64 + k0];
        *(float4*)&efs[le * 72 + k0] = efv;
    }
    __syncthreads();
    if (e >= e1) return;
    float a0 = bs[k0], a1 = bs[k0 + 1], a2 = bs[k0 + 2], a3 = bs[k0 + 3];
#pragma unroll
    for (int f = 0; f < 64; ++f) {
        float ev = efs[le * 72 + f];
        float4 wv = *(const float4*)&Ws[f * 64 + k0];
        a0 += ev * wv.x; a1 += ev * wv.y; a2 += ev * wv.z; a3 += ev * wv.w;
    }
    size_t qi = (size_t)(e - e0) * 64 + k0;
    *(__half2*)&q[qi]     = __floats2half2_rn(a0 * a0, a1 * a1);
    *(__half2*)&q[qi + 2] = __floats2half2_rn(a2 * a2, a3 * a3);
}

// ---------------- per-edge similarity -> vals (both halves) ----------------
__global__ void k_sim(const float* __restrict__ x, const __half* __restrict__ q,
                      const int* __restrict__ edge_row, const float* __restrict__ L0,
                      float* __restrict__ vals, int e0, int e1) {
    int t = threadIdx.x;
    int le = t >> 4, kq = t & 15, k0 = kq * 4;
    int e = e0 + blockIdx.x * 16 + le;
    if (e >= e1) return;
    int row = edge_row[e];
    const float4 rn = *(const float4*)&x[(size_t)row * 64 + k0];
    const float4 cn = *(const float4*)&x[(size_t)(row - NUSERS) * 64 + k0];
    size_t qi = (size_t)(e - e0) * 64 + k0;
    float2 q01 = __half22float2(*(const __half2*)&q[qi]);
    float2 q23 = __half22float2(*(const __half2*)&q[qi + 2]);
    float aa = rn.x * rn.x * q01.x + rn.y * rn.y * q01.y + rn.z * rn.z * q23.x + rn.w * rn.w * q23.y;
    float bb = cn.x * cn.x * q01.x + cn.y * cn.y * q01.y + cn.z * cn.z * q23.x + cn.w * cn.w * q23.y;
    float ab = rn.x * cn.x * q01.x + rn.y * cn.y * q01.y + rn.z * cn.z * q23.x + rn.w * cn.w * q23.y;
#pragma unroll
    for (int m = 1; m < 16; m <<= 1) {
        aa += __shfl_xor(aa, m, 64);
        bb += __shfl_xor(bb, m, 64);
        ab += __shfl_xor(ab, m, 64);
    }
    if (kq == 0) {
        float na = fmaxf(sqrtf(aa), EPSV);
        float nb = fmaxf(sqrtf(bb), EPSV);
        float sim = fmaxf(ab / (na * nb), 0.0f);
        vals[e]      = 0.5f * L0[e]      + 0.5f * sim;
        vals[e + EH] = 0.5f * L0[e + EH] + 0.5f * sim;
    }
}

// ---------------- degree + dinv ----------------
__global__ void k_deg(const int* __restrict__ edge_row, const float* __restrict__ vals,
                      float* __restrict__ deg) {
    int e = blockIdx.x * 256 + threadIdx.x;
    if (e < E2) atomicAdd(&deg[edge_row[e]], vals[e]);
}

__global__ void k_dinv(const float* __restrict__ deg, float* __restrict__ dinv) {
    int n = blockIdx.x * 256 + threadIdx.x;
    if (n < NNODES) {
        float d = deg[n];
        dinv[n] = d > 0.0f ? rsqrtf(d) : 0.0f;
    }
}

// ---------------- h = x @ W_l ----------------
__global__ void k_h(const float* __restrict__ x, const float* __restrict__ W,
                    float* __restrict__ h) {
    __shared__ float Ws[4096];
    __shared__ float xs[16 * 72];
    int t = threadIdx.x;
    for (int i = t; i < 4096; i += 256) Ws[i] = W[i];
    int le = t >> 4, kq = t & 15, k0 = kq * 4;
    int n = blockIdx.x * 16 + le;
    if (n < NNODES)
        *(float4*)&xs[le * 72 + k0] = *(const float4*)&x[(size_t)n * 64 + k0];
    __syncthreads();
    if (n >= NNODES) return;
    float a0 = 0, a1 = 0, a2 = 0, a3 = 0;
#pragma unroll
    for (int f = 0; f < 64; ++f) {
        float xv = xs[le * 72 + f];
        float4 wv = *(const float4*)&Ws[f * 64 + k0];
        a0 += xv * wv.x; a1 += xv * wv.y; a2 += xv * wv.z; a3 += xv * wv.w;
    }
    float4 o = make_float4(a0, a1, a2, a3);
    *(float4*)&h[(size_t)n * 64 + k0] = o;
}

// ---------------- CSR aggregation + bias + relu ----------------
__global__ void k_agg(const int* __restrict__ offsets, const int2* __restrict__ csr,
                      const float* __restrict__ vals, const float* __restrict__ dinv,
                      const float* __restrict__ h, const float* __restrict__ bias,
                      float* __restrict__ xo) {
    int t = threadIdx.x;
    int n = blockIdx.x * 4 + (t >> 6);
    int lane = t & 63;
    if (n >= NNODES) return;
    float dn = dinv[n];
    int jb = offsets[n], je = offsets[n + 1];
    float acc = 0.0f;
    for (int j = jb; j < je; ++j) {
        int2 ce = csr[j];
        float wgt = dn * vals[ce.y] * dinv[ce.x];
        acc += wgt * h[(size_t)ce.x * 64 + lane];
    }
    xo[(size_t)n * 64 + lane] = fmaxf(acc + bias[lane], 0.0f);
}

// ---------------- final batched dot ----------------
__global__ void k_final(const float* __restrict__ x, const int* __restrict__ uidx,
                        const int* __restrict__ iidx, const float* __restrict__ Bu,
                        const float* __restrict__ Bi, const float* __restrict__ Mu,
                        float* __restrict__ out) {
    int t = threadIdx.x;
    int le = t >> 4, kq = t & 15, k0 = kq * 4;
    int i = blockIdx.x * 16 + le;
    if (i >= NBATCH) return;
    int u = uidx[i], it = iidx[i];
    float4 a = *(const float4*)&x[(size_t)u * 64 + k0];
    float4 b = *(const float4*)&x[(size_t)(NUSERS + it) * 64 + k0];
    float d = a.x * b.x + a.y * b.y + a.z * b.z + a.w * b.w;
#pragma unroll
    for (int m = 1; m < 16; m <<= 1) d += __shfl_xor(d, m, 64);
    if (kq == 0) out[i] = d + Bu[u] + Bi[it] + Mu[0];
}

extern "C" void kernel_launch(void* const* d_in, const int* in_sizes, int n_in,
                              void* d_out, int out_size, void* d_ws, size_t ws_size,
                              hipStream_t stream) {
    const float* Gu    = (const float*)d_in[0];
    const float* Gi    = (const float*)d_in[1];
    const float* Bu    = (const float*)d_in[2];
    const float* Bi    = (const float*)d_in[3];
    const float* Mu    = (const float*)d_in[4];
    const float* projW = (const float*)d_in[5];
    const float* projb = (const float*)d_in[6];
    const float* gcnW  = (const float*)d_in[7];
    const float* gcnb  = (const float*)d_in[8];
    const float* ef    = (const float*)d_in[9];
    const float* L0    = (const float*)d_in[10];
    const int*   erow  = (const int*)d_in[11];
    const int*   ecol  = (const int*)d_in[12];
    const int*   uidx  = (const int*)d_in[13];
    const int*   iidx  = (const int*)d_in[14];
    float* out = (float*)d_out;

    char* w = (char*)d_ws;
    size_t off = 0;
    auto take = [&](size_t bytes) -> void* {
        void* p = w + off;
        off += (bytes + 255) & ~(size_t)255;
        return p;
    };
    float* x0      = (float*)take((size_t)NNODES * KDIM * 4);
    float* x1      = (float*)take((size_t)NNODES * KDIM * 4);
    float* h       = (float*)take((size_t)NNODES * KDIM * 4);
    float* vals    = (float*)take((size_t)E2 * 4);
    float* deg     = (float*)take((size_t)NNODES * 4);
    float* dinv    = (float*)take((size_t)NNODES * 4);
    int*   counts  = (int*)take((size_t)NNODES * 4);
    int*   offsets = (int*)take((size_t)(NNODES + 1) * 4);
    int*   cursor  = (int*)take((size_t)(NNODES + 1) * 4);
    int2*  csr     = (int2*)take((size_t)E2 * 8);
    __half* q = (__half*)(w + off);
    size_t rem = ws_size > off ? ws_size - off : 0;
    size_t qcap = rem / (KDIM * 2);
    if (qcap > (size_t)EH) qcap = EH;
    qcap &= ~(size_t)15;
    if (qcap < 16) qcap = 16;  // avoid div-by-zero; ws assumed >= ~96MB
    int nch = (int)(((size_t)EH + qcap - 1) / qcap);

    // CSR build (structure is layer-invariant)
    hipMemsetAsync(counts, 0, NNODES * 4, stream);
    k_count<<<(E2 + 255) / 256, 256, 0, stream>>>(erow, counts);
    k_scan<<<1, 1024, 0, stream>>>(counts, offsets, cursor);
    k_fill<<<(E2 + 255) / 256, 256, 0, stream>>>(erow, ecol, cursor, csr);

    // x0 = concat(Gu, Gi)
    hipMemcpyAsync(x0, Gu, (size_t)NUSERS * KDIM * 4, hipMemcpyDeviceToDevice, stream);
    hipMemcpyAsync(x0 + (size_t)NUSERS * KDIM, Gi, (size_t)NITEMS * KDIM * 4,
                   hipMemcpyDeviceToDevice, stream);

    if (nch == 1)
        k_projq<<<(EH + 15) / 16, 256, 0, stream>>>(ef, projW, projb, q, 0, EH);

    float* xc = x0;
    float* xn = x1;
    for (int l = 0; l < 3; ++l) {
        for (int c = 0; c < nch; ++c) {
            int e0 = (int)((size_t)c * qcap);
            size_t e1s = (size_t)(c + 1) * qcap;
            int e1 = (int)(e1s < (size_t)EH ? e1s : (size_t)EH);
            int ne = e1 - e0;
            if (ne <= 0) continue;
            if (nch > 1)
                k_projq<<<(ne + 15) / 16, 256, 0, stream>>>(ef, projW, projb, q, e0, e1);
            k_sim<<<(ne + 15) / 16, 256, 0, stream>>>(xc, q, erow, L0, vals, e0, e1);
        }
        hipMemsetAsync(deg, 0, NNODES * 4, stream);
        k_deg<<<(E2 + 255) / 256, 256, 0, stream>>>(erow, vals, deg);
        k_dinv<<<(NNODES + 255) / 256, 256, 0, stream>>>(deg, dinv);
        k_h<<<(NNODES + 15) / 16, 256, 0, stream>>>(xc, gcnW + (size_t)l * 4096, h);
        k_agg<<<(NNODES + 3) / 4, 256, 0, stream>>>(offsets, csr, vals, dinv, h,
                                                    gcnb + (size_t)l * 64, xn);
        float* tswap = xc; xc = xn; xn = tswap;
    }
    k_final<<<(NBATCH + 15) / 16, 256, 0, stream>>>(xc, uidx, iidx, Bu, Bi, Mu, out);
}

// Round 2
// 1158.410 us; speedup vs baseline: 1.5993x; 1.5993x over previous
//
#include <hip/hip_runtime.h>
#include <hip/hip_fp16.h>

#define NUSERS 60000
#define NITEMS 30000
#define NNODES 90000
#define KDIM 64
#define EH 1000000
#define E2 2000000
#define NBATCH 100000
#define EPSV 1e-8f
#define NPAD 94208  // 4096*23 >= NNODES+4096, for unguarded int4 scan loads

typedef __attribute__((ext_vector_type(8))) short short8v;
typedef __attribute__((ext_vector_type(4))) float f32x4;

// ---------------- CSR build ----------------
__global__ void k_count(const int* __restrict__ edge_row, int* __restrict__ counts) {
    int e = blockIdx.x * 256 + threadIdx.x;
    if (e < E2) atomicAdd(&counts[edge_row[e]], 1);
}

// single-block scan: 1024 threads x 4 elems = 4096/chunk, 22 chunks
__global__ void k_scan(const int* __restrict__ counts, int* __restrict__ offsets,
                       int* __restrict__ cursor) {
    __shared__ int wsum[17];
    int t = threadIdx.x;
    int lane = t & 63, wid = t >> 6;  // 16 waves
    int carry = 0;
    for (int base = 0; base < NNODES; base += 4096) {
        int i0 = base + t * 4;
        int4 v = *(const int4*)&counts[i0];  // padded, safe
        int s0 = v.x, s1 = s0 + v.y, s2 = s1 + v.z, s3 = s2 + v.w;
        int ws = s3;
#pragma unroll
        for (int o = 1; o < 64; o <<= 1) {
            int u = __shfl_up(ws, o, 64);
            if (lane >= o) ws += u;
        }
        if (lane == 63) wsum[wid] = ws;
        __syncthreads();
        if (wid == 0) {
            int wv = (lane < 16) ? wsum[lane] : 0;
#pragma unroll
            for (int o = 1; o < 16; o <<= 1) {
                int u = __shfl_up(wv, o, 64);
                if (lane >= o) wv += u;
            }
            if (lane < 16) wsum[lane] = wv;
            if (lane == 15) wsum[16] = wv;
        }
        __syncthreads();
        int wbase = (wid > 0) ? wsum[wid - 1] : 0;
        int texcl = carry + wbase + (ws - s3);
        if (i0 < NNODES)     { offsets[i0]     = texcl;      cursor[i0]     = texcl; }
        if (i0 + 1 < NNODES) { offsets[i0 + 1] = texcl + s0; cursor[i0 + 1] = texcl + s0; }
        if (i0 + 2 < NNODES) { offsets[i0 + 2] = texcl + s1; cursor[i0 + 2] = texcl + s1; }
        if (i0 + 3 < NNODES) { offsets[i0 + 3] = texcl + s2; cursor[i0 + 3] = texcl + s2; }
        carry += wsum[16];
        __syncthreads();
    }
    if (t == 0) offsets[NNODES] = carry;
}

__global__ void k_fill(const int* __restrict__ edge_row, const int* __restrict__ edge_col,
                       int* __restrict__ cursor, int2* __restrict__ csr) {
    int e = blockIdx.x * 256 + threadIdx.x;
    if (e >= E2) return;
    int r = edge_row[e];
    int slot = atomicAdd(&cursor[r], 1);
    csr[slot] = make_int2(edge_col[e], e);
}

// ---------------- MFMA 64-col GEMM: out = A(Mx64) @ W(64x64) [+bias, ^2->fp16] ----
// MODE 0: h = x@W, f32 out.  MODE 1: q = (ef@W+b)^2, fp16 out.
// bf16 hi/lo split (3 passes) for ~2^-16 relative accuracy.
template <int MODE>
__global__ void k_gemm(const float* __restrict__ A, const float* __restrict__ W,
                       const float* __restrict__ bias, void* __restrict__ out, int M) {
    __shared__ float Ws[4096];
    int t = threadIdx.x;
    for (int i = t; i < 4096; i += 256) Ws[i] = W[i];
    __syncthreads();
    int lane = t & 63;
    int wid = t >> 6;
    int lr = lane & 15;  // row-in-tile (A) / col-in-tile (B,D)
    int kg = lane >> 4;  // k-group of 8
    // B fragments, hi/lo, [kt][ct]
    short8v Bh[2][4], Bl[2][4];
#pragma unroll
    for (int kt = 0; kt < 2; ++kt)
#pragma unroll
        for (int ct = 0; ct < 4; ++ct) {
            short8v bh, bl;
#pragma unroll
            for (int i = 0; i < 8; ++i) {
                int k = kt * 32 + kg * 8 + i;
                float v = Ws[k * 64 + ct * 16 + lr];
                unsigned u = __float_as_uint(v);
                float d = v - __uint_as_float(u & 0xffff0000u);
                bh[i] = (short)(u >> 16);
                bl[i] = (short)(__float_as_uint(d) >> 16);
            }
            Bh[kt][ct] = bh;
            Bl[kt][ct] = bl;
        }
    float bcol[4];
    if (MODE == 1) {
#pragma unroll
        for (int ct = 0; ct < 4; ++ct) bcol[ct] = bias[ct * 16 + lr];
    }
    int nt = M >> 4;
    int nw = gridDim.x * 4;
    for (int tile = blockIdx.x * 4 + wid; tile < nt; tile += nw) {
        int r0 = tile << 4;
        const float* ap = &A[(size_t)(r0 + lr) * 64 + kg * 8];
        float4 a0 = *(const float4*)ap;
        float4 a1 = *(const float4*)(ap + 4);
        float4 a2 = *(const float4*)(ap + 32);
        float4 a3 = *(const float4*)(ap + 36);
        float av[16] = {a0.x, a0.y, a0.z, a0.w, a1.x, a1.y, a1.z, a1.w,
                        a2.x, a2.y, a2.z, a2.w, a3.x, a3.y, a3.z, a3.w};
        short8v Ah[2], Al[2];
#pragma unroll
        for (int kt = 0; kt < 2; ++kt) {
            short8v ah, al;
#pragma unroll
            for (int i = 0; i < 8; ++i) {
                float v = av[kt * 8 + i];
                unsigned u = __float_as_uint(v);
                float d = v - __uint_as_float(u & 0xffff0000u);
                ah[i] = (short)(u >> 16);
                al[i] = (short)(__float_as_uint(d) >> 16);
            }
            Ah[kt] = ah;
            Al[kt] = al;
        }
        f32x4 acc[4] = {{0, 0, 0, 0}, {0, 0, 0, 0}, {0, 0, 0, 0}, {0, 0, 0, 0}};
#pragma unroll
        for (int kt = 0; kt < 2; ++kt)
#pragma unroll
            for (int ct = 0; ct < 4; ++ct) {
                acc[ct] = __builtin_amdgcn_mfma_f32_16x16x32_bf16(Ah[kt], Bh[kt][ct], acc[ct], 0, 0, 0);
                acc[ct] = __builtin_amdgcn_mfma_f32_16x16x32_bf16(Al[kt], Bh[kt][ct], acc[ct], 0, 0, 0);
                acc[ct] = __builtin_amdgcn_mfma_f32_16x16x32_bf16(Ah[kt], Bl[kt][ct], acc[ct], 0, 0, 0);
            }
        // D layout (m89-verified): col = ct*16 + (lane&15), row = r0 + (lane>>4)*4 + r
#pragma unroll
        for (int ct = 0; ct < 4; ++ct)
#pragma unroll
            for (int r = 0; r < 4; ++r) {
                int row = r0 + kg * 4 + r;
                int col = ct * 16 + lr;
                float p = acc[ct][r];
                if (MODE == 1) {
                    p += bcol[ct];
                    ((__half*)out)[(size_t)row * 64 + col] = __float2half(p * p);
                } else {
                    ((float*)out)[(size_t)row * 64 + col] = p;
                }
            }
    }
}

// ---------------- per-edge similarity -> vals + fused degree atomics ----------------
__global__ void k_sim(const float* __restrict__ x, const __half* __restrict__ q,
                      const int* __restrict__ edge_row, const int* __restrict__ edge_col,
                      const float* __restrict__ L0, float* __restrict__ vals,
                      float* __restrict__ deg) {
    int t = threadIdx.x;
    int le = t >> 4, kq = t & 15, k0 = kq * 4;
    int e = blockIdx.x * 16 + le;
    if (e >= EH) return;
    int row = edge_row[e];
    const float4 rn = *(const float4*)&x[(size_t)row * 64 + k0];
    const float4 cn = *(const float4*)&x[(size_t)(row - NUSERS) * 64 + k0];
    size_t qi = (size_t)e * 64 + k0;
    float2 q01 = __half22float2(*(const __half2*)&q[qi]);
    float2 q23 = __half22float2(*(const __half2*)&q[qi + 2]);
    float aa = rn.x * rn.x * q01.x + rn.y * rn.y * q01.y + rn.z * rn.z * q23.x + rn.w * rn.w * q23.y;
    float bb = cn.x * cn.x * q01.x + cn.y * cn.y * q01.y + cn.z * cn.z * q23.x + cn.w * cn.w * q23.y;
    float ab = rn.x * cn.x * q01.x + rn.y * cn.y * q01.y + rn.z * cn.z * q23.x + rn.w * cn.w * q23.y;
#pragma unroll
    for (int m = 1; m < 16; m <<= 1) {
        aa += __shfl_xor(aa, m, 64);
        bb += __shfl_xor(bb, m, 64);
        ab += __shfl_xor(ab, m, 64);
    }
    if (kq == 0) {
        float na = fmaxf(sqrtf(aa), EPSV);
        float nb = fmaxf(sqrtf(bb), EPSV);
        float sim = fmaxf(ab / (na * nb), 0.0f);
        float v1 = 0.5f * L0[e] + 0.5f * sim;
        float v2 = 0.5f * L0[e + EH] + 0.5f * sim;
        vals[e] = v1;
        vals[e + EH] = v2;
        atomicAdd(&deg[row], v1);          // edge_row[e]
        atomicAdd(&deg[edge_col[e]], v2);  // edge_row[e+EH] == edge_col[e]
    }
}

__global__ void k_dinv(const float* __restrict__ deg, float* __restrict__ dinv) {
    int n = blockIdx.x * 256 + threadIdx.x;
    if (n < NNODES) {
        float d = deg[n];
        dinv[n] = d > 0.0f ? rsqrtf(d) : 0.0f;
    }
}

// ---------------- CSR aggregation + bias + relu: 2 nodes/wave, float2 lanes ----------
__global__ void k_agg(const int* __restrict__ offsets, const int2* __restrict__ csr,
                      const float* __restrict__ vals, const float* __restrict__ dinv,
                      const float* __restrict__ h, const float* __restrict__ bias,
                      float* __restrict__ xo) {
    int t = threadIdx.x;
    int wid = t >> 6, sub = (t >> 5) & 1, sl = t & 31;
    int n = blockIdx.x * 8 + wid * 2 + sub;
    if (n >= NNODES) return;
    float dn = dinv[n];
    int jb = offsets[n], je = offsets[n + 1];
    const float2* h2 = (const float2*)h;
    float2 acc = make_float2(0.0f, 0.0f);
    for (int j = jb; j < je; ++j) {
        int2 ce = csr[j];
        float wgt = dn * vals[ce.y] * dinv[ce.x];
        float2 hv = h2[(size_t)ce.x * 32 + sl];
        acc.x += wgt * hv.x;
        acc.y += wgt * hv.y;
    }
    float2 bv = ((const float2*)bias)[sl];
    float2 o = make_float2(fmaxf(acc.x + bv.x, 0.0f), fmaxf(acc.y + bv.y, 0.0f));
    ((float2*)xo)[(size_t)n * 32 + sl] = o;
}

// ---------------- final batched dot ----------------
__global__ void k_final(const float* __restrict__ x, const int* __restrict__ uidx,
                        const int* __restrict__ iidx, const float* __restrict__ Bu,
                        const float* __restrict__ Bi, const float* __restrict__ Mu,
                        float* __restrict__ out) {
    int t = threadIdx.x;
    int le = t >> 4, kq = t & 15, k0 = kq * 4;
    int i = blockIdx.x * 16 + le;
    if (i >= NBATCH) return;
    int u = uidx[i], it = iidx[i];
    float4 a = *(const float4*)&x[(size_t)u * 64 + k0];
    float4 b = *(const float4*)&x[(size_t)(NUSERS + it) * 64 + k0];
    float d = a.x * b.x + a.y * b.y + a.z * b.z + a.w * b.w;
#pragma unroll
    for (int m = 1; m < 16; m <<= 1) d += __shfl_xor(d, m, 64);
    if (kq == 0) out[i] = d + Bu[u] + Bi[it] + Mu[0];
}

extern "C" void kernel_launch(void* const* d_in, const int* in_sizes, int n_in,
                              void* d_out, int out_size, void* d_ws, size_t ws_size,
                              hipStream_t stream) {
    const float* Gu    = (const float*)d_in[0];
    const float* Gi    = (const float*)d_in[1];
    const float* Bu    = (const float*)d_in[2];
    const float* Bi    = (const float*)d_in[3];
    const float* Mu    = (const float*)d_in[4];
    const float* projW = (const float*)d_in[5];
    const float* projb = (const float*)d_in[6];
    const float* gcnW  = (const float*)d_in[7];
    const float* gcnb  = (const float*)d_in[8];
    const float* ef    = (const float*)d_in[9];
    const float* L0    = (const float*)d_in[10];
    const int*   erow  = (const int*)d_in[11];
    const int*   ecol  = (const int*)d_in[12];
    const int*   uidx  = (const int*)d_in[13];
    const int*   iidx  = (const int*)d_in[14];
    float* out = (float*)d_out;

    char* w = (char*)d_ws;
    size_t off = 0;
    auto take = [&](size_t bytes) -> void* {
        void* p = w + off;
        off += (bytes + 255) & ~(size_t)255;
        return p;
    };
    float* x0      = (float*)take((size_t)NNODES * KDIM * 4);
    float* x1      = (float*)take((size_t)NNODES * KDIM * 4);
    float* h       = (float*)take((size_t)NNODES * KDIM * 4);
    float* vals    = (float*)take((size_t)E2 * 4);
    float* deg     = (float*)take((size_t)NNODES * 4);
    float* dinv    = (float*)take((size_t)NNODES * 4);
    int*   counts  = (int*)take((size_t)NPAD * 4);
    int*   offsets = (int*)take((size_t)(NNODES + 1) * 4);
    int*   cursor  = (int*)take((size_t)(NNODES + 1) * 4);
    int2*  csr     = (int2*)take((size_t)E2 * 8);
    __half* q      = (__half*)take((size_t)EH * KDIM * 2);

    // CSR build (structure is layer-invariant)
    hipMemsetAsync(counts, 0, (size_t)NPAD * 4, stream);
    k_count<<<(E2 + 255) / 256, 256, 0, stream>>>(erow, counts);
    k_scan<<<1, 1024, 0, stream>>>(counts, offsets, cursor);
    k_fill<<<(E2 + 255) / 256, 256, 0, stream>>>(erow, ecol, cursor, csr);

    // x0 = concat(Gu, Gi)
    hipMemcpyAsync(x0, Gu, (size_t)NUSERS * KDIM * 4, hipMemcpyDeviceToDevice, stream);
    hipMemcpyAsync(x0 + (size_t)NUSERS * KDIM, Gi, (size_t)NITEMS * KDIM * 4,
                   hipMemcpyDeviceToDevice, stream);

    // q = (ef @ projW + projb)^2 in fp16
    k_gemm<1><<<1024, 256, 0, stream>>>(ef, projW, projb, q, EH);

    float* xc = x0;
    float* xn = x1;
    for (int l = 0; l < 3; ++l) {
        hipMemsetAsync(deg, 0, NNODES * 4, stream);
        k_sim<<<(EH + 15) / 16, 256, 0, stream>>>(xc, q, erow, ecol, L0, vals, deg);
        k_dinv<<<(NNODES + 255) / 256, 256, 0, stream>>>(deg, dinv);
        k_gemm<0><<<512, 256, 0, stream>>>(xc, gcnW + (size_t)l * 4096, nullptr, h, NNODES);
        k_agg<<<(NNODES + 7) / 8, 256, 0, stream>>>(offsets, csr, vals, dinv, h,
                                                    gcnb + (size_t)l * 64, xn);
        float* tswap = xc; xc = xn; xn = tswap;
    }
    k_final<<<(NBATCH + 15) / 16, 256, 0, stream>>>(xc, uidx, iidx, Bu, Bi, Mu, out);
}

// Round 3
// 984.491 us; speedup vs baseline: 1.8818x; 1.1767x over previous
//
#include <hip/hip_runtime.h>
#include <hip/hip_fp16.h>

#define NUSERS 60000
#define NITEMS 30000
#define NNODES 90000
#define KDIM 64
#define EH 1000000
#define E2 2000000
#define NBATCH 100000
#define EPSV 1e-8f
#define NPAD 94208  // 4096*23 >= NNODES+4096, for unguarded int4 scan loads

#define NB 128     // coarse buckets for CSR build
#define RPB 704    // rows per bucket: 128*704 = 90112 >= NNODES
#define CHUNK 2048 // edges per block-round in pass A

typedef __attribute__((ext_vector_type(8))) short short8v;
typedef __attribute__((ext_vector_type(4))) float f32x4;

// ---------------- CSR build ----------------
__global__ void k_count(const int* __restrict__ edge_row, int* __restrict__ counts) {
    int e = blockIdx.x * 256 + threadIdx.x;
    if (e < E2) atomicAdd(&counts[edge_row[e]], 1);
}

// single-block scan: 1024 threads x 4 elems = 4096/chunk, 22 chunks
__global__ void k_scan(const int* __restrict__ counts, int* __restrict__ offsets,
                       int* __restrict__ cursor) {
    __shared__ int wsum[17];
    int t = threadIdx.x;
    int lane = t & 63, wid = t >> 6;  // 16 waves
    int carry = 0;
    for (int base = 0; base < NNODES; base += 4096) {
        int i0 = base + t * 4;
        int4 v = *(const int4*)&counts[i0];  // padded, safe
        int s0 = v.x, s1 = s0 + v.y, s2 = s1 + v.z, s3 = s2 + v.w;
        int ws = s3;
#pragma unroll
        for (int o = 1; o < 64; o <<= 1) {
            int u = __shfl_up(ws, o, 64);
            if (lane >= o) ws += u;
        }
        if (lane == 63) wsum[wid] = ws;
        __syncthreads();
        if (wid == 0) {
            int wv = (lane < 16) ? wsum[lane] : 0;
#pragma unroll
            for (int o = 1; o < 16; o <<= 1) {
                int u = __shfl_up(wv, o, 64);
                if (lane >= o) wv += u;
            }
            if (lane < 16) wsum[lane] = wv;
            if (lane == 15) wsum[16] = wv;
        }
        __syncthreads();
        int wbase = (wid > 0) ? wsum[wid - 1] : 0;
        int texcl = carry + wbase + (ws - s3);
        if (i0 < NNODES)     { offsets[i0]     = texcl;      cursor[i0]     = texcl; }
        if (i0 + 1 < NNODES) { offsets[i0 + 1] = texcl + s0; cursor[i0 + 1] = texcl + s0; }
        if (i0 + 2 < NNODES) { offsets[i0 + 2] = texcl + s1; cursor[i0 + 2] = texcl + s1; }
        if (i0 + 3 < NNODES) { offsets[i0 + 3] = texcl + s2; cursor[i0 + 3] = texcl + s2; }
        carry += wsum[16];
        __syncthreads();
    }
    if (t == 0) offsets[NNODES] = carry;
}

__global__ void k_bcur(const int* __restrict__ offsets, int* __restrict__ gcur) {
    int t = threadIdx.x;
    if (t < NB) gcur[t] = offsets[t * RPB];
}

// Pass A: LDS counting-sort of 2048-edge chunks into NB buckets, coalesced append
// into each bucket's final CSR region (staging: srow + sce).
__global__ void k_binA(const int* __restrict__ erow, const int* __restrict__ ecol,
                       int* __restrict__ gcur, int* __restrict__ srow,
                       int2* __restrict__ sce) {
    __shared__ int bcnt[NB];
    __shared__ int bbase[NB];
    __shared__ int bpos[NB];
    __shared__ int bglob[NB];
    __shared__ int wtot[2];
    __shared__ int lrow[CHUNK];
    __shared__ int2 lce[CHUNK];
    int t = threadIdx.x;
    for (int base = blockIdx.x * CHUNK; base < E2; base += gridDim.x * CHUNK) {
        for (int i = t; i < NB; i += 256) bcnt[i] = 0;
        __syncthreads();
        int mr[8], mc[8], me[8], mb[8];
#pragma unroll
        for (int k = 0; k < 8; ++k) {
            int e = base + k * 256 + t;
            if (e < E2) {
                mr[k] = erow[e];
                mc[k] = ecol[e];
                me[k] = e;
                mb[k] = mr[k] / RPB;
                atomicAdd(&bcnt[mb[k]], 1);
            } else {
                mb[k] = -1;
            }
        }
        __syncthreads();
        if (t < NB) {  // 2 full waves scan NB=128 counts
            int v = bcnt[t];
            int s = v;
#pragma unroll
            for (int o = 1; o < 64; o <<= 1) {
                int u = __shfl_up(s, o, 64);
                if ((t & 63) >= o) s += u;
            }
            bbase[t] = s - v;
            if ((t & 63) == 63) wtot[t >> 6] = s;
        }
        __syncthreads();
        if (t >= 64 && t < NB) bbase[t] += wtot[0];
        if (t < NB) bpos[t] = 0;
        __syncthreads();
#pragma unroll
        for (int k = 0; k < 8; ++k) {
            if (mb[k] >= 0) {
                int p = bbase[mb[k]] + atomicAdd(&bpos[mb[k]], 1);
                lrow[p] = mr[k];
                lce[p] = make_int2(mc[k], me[k]);
            }
        }
        __syncthreads();
        if (t < NB) bglob[t] = bcnt[t] ? atomicAdd(&gcur[t], bcnt[t]) : 0;
        __syncthreads();
        int total = bbase[NB - 1] + bcnt[NB - 1];
        for (int i = t; i < total; i += 256) {
            int r = lrow[i];
            int b = r / RPB;
            int dest = bglob[b] + (i - bbase[b]);
            srow[dest] = r;
            sce[dest] = lce[i];
        }
        __syncthreads();
    }
}

// Pass B: one block per bucket; scattered writes confined to ~125KB window (L2-resident)
__global__ void k_binB(const int* __restrict__ srow, const int2* __restrict__ sce,
                       const int* __restrict__ offsets, int* __restrict__ cursor,
                       int2* __restrict__ csr) {
    int b = blockIdx.x;
    int r1 = (b + 1) * RPB;
    if (r1 > NNODES) r1 = NNODES;
    int lo = offsets[b * RPB], hi = offsets[r1];
    for (int i = lo + threadIdx.x; i < hi; i += blockDim.x) {
        int r = srow[i];
        int2 ce = sce[i];
        int slot = atomicAdd(&cursor[r], 1);
        csr[slot] = ce;
    }
}

// ---------------- MFMA 64-col GEMM: out = A(Mx64) @ W(64x64) [+bias, ^2->fp16] ----
// MODE 0: h = x@W, fp16 out.  MODE 1: q = (ef@W+b)^2, fp16 out.
// bf16 hi/lo split (3 passes) for ~2^-16 relative accuracy.
template <int MODE>
__global__ void k_gemm(const float* __restrict__ A, const float* __restrict__ W,
                       const float* __restrict__ bias, void* __restrict__ out, int M) {
    __shared__ float Ws[4096];
    int t = threadIdx.x;
    for (int i = t; i < 4096; i += 256) Ws[i] = W[i];
    __syncthreads();
    int lane = t & 63;
    int wid = t >> 6;
    int lr = lane & 15;  // row-in-tile (A) / col-in-tile (B,D)
    int kg = lane >> 4;  // k-group of 8
    short8v Bh[2][4], Bl[2][4];
#pragma unroll
    for (int kt = 0; kt < 2; ++kt)
#pragma unroll
        for (int ct = 0; ct < 4; ++ct) {
            short8v bh, bl;
#pragma unroll
            for (int i = 0; i < 8; ++i) {
                int k = kt * 32 + kg * 8 + i;
                float v = Ws[k * 64 + ct * 16 + lr];
                unsigned u = __float_as_uint(v);
                float d = v - __uint_as_float(u & 0xffff0000u);
                bh[i] = (short)(u >> 16);
                bl[i] = (short)(__float_as_uint(d) >> 16);
            }
            Bh[kt][ct] = bh;
            Bl[kt][ct] = bl;
        }
    float bcol[4];
    if (MODE == 1) {
#pragma unroll
        for (int ct = 0; ct < 4; ++ct) bcol[ct] = bias[ct * 16 + lr];
    }
    int nt = M >> 4;
    int nw = gridDim.x * 4;
    for (int tile = blockIdx.x * 4 + wid; tile < nt; tile += nw) {
        int r0 = tile << 4;
        const float* ap = &A[(size_t)(r0 + lr) * 64 + kg * 8];
        float4 a0 = *(const float4*)ap;
        float4 a1 = *(const float4*)(ap + 4);
        float4 a2 = *(const float4*)(ap + 32);
        float4 a3 = *(const float4*)(ap + 36);
        float av[16] = {a0.x, a0.y, a0.z, a0.w, a1.x, a1.y, a1.z, a1.w,
                        a2.x, a2.y, a2.z, a2.w, a3.x, a3.y, a3.z, a3.w};
        short8v Ah[2], Al[2];
#pragma unroll
        for (int kt = 0; kt < 2; ++kt) {
            short8v ah, al;
#pragma unroll
            for (int i = 0; i < 8; ++i) {
                float v = av[kt * 8 + i];
                unsigned u = __float_as_uint(v);
                float d = v - __uint_as_float(u & 0xffff0000u);
                ah[i] = (short)(u >> 16);
                al[i] = (short)(__float_as_uint(d) >> 16);
            }
            Ah[kt] = ah;
            Al[kt] = al;
        }
        f32x4 acc[4] = {{0, 0, 0, 0}, {0, 0, 0, 0}, {0, 0, 0, 0}, {0, 0, 0, 0}};
#pragma unroll
        for (int kt = 0; kt < 2; ++kt)
#pragma unroll
            for (int ct = 0; ct < 4; ++ct) {
                acc[ct] = __builtin_amdgcn_mfma_f32_16x16x32_bf16(Ah[kt], Bh[kt][ct], acc[ct], 0, 0, 0);
                acc[ct] = __builtin_amdgcn_mfma_f32_16x16x32_bf16(Al[kt], Bh[kt][ct], acc[ct], 0, 0, 0);
                acc[ct] = __builtin_amdgcn_mfma_f32_16x16x32_bf16(Ah[kt], Bl[kt][ct], acc[ct], 0, 0, 0);
            }
        // D layout (m89-verified): col = ct*16 + (lane&15), row = r0 + (lane>>4)*4 + r
#pragma unroll
        for (int ct = 0; ct < 4; ++ct)
#pragma unroll
            for (int r = 0; r < 4; ++r) {
                int row = r0 + kg * 4 + r;
                int col = ct * 16 + lr;
                float p = acc[ct][r];
                if (MODE == 1) {
                    p += bcol[ct];
                    ((__half*)out)[(size_t)row * 64 + col] = __float2half(p * p);
                } else {
                    ((__half*)out)[(size_t)row * 64 + col] = __float2half(p);
                }
            }
    }
}

// ---------------- per-edge similarity -> vals + fused degree atomics ----------------
__global__ void k_sim(const float* __restrict__ x, const __half* __restrict__ q,
                      const int* __restrict__ edge_row, const int* __restrict__ edge_col,
                      const float* __restrict__ L0, float* __restrict__ vals,
                      float* __restrict__ deg) {
    int t = threadIdx.x;
    int le = t >> 4, kq = t & 15, k0 = kq * 4;
    int e = blockIdx.x * 16 + le;
    if (e >= EH) return;
    int row = edge_row[e];
    const float4 rn = *(const float4*)&x[(size_t)row * 64 + k0];
    const float4 cn = *(const float4*)&x[(size_t)(row - NUSERS) * 64 + k0];
    size_t qi = (size_t)e * 64 + k0;
    float2 q01 = __half22float2(*(const __half2*)&q[qi]);
    float2 q23 = __half22float2(*(const __half2*)&q[qi + 2]);
    float aa = rn.x * rn.x * q01.x + rn.y * rn.y * q01.y + rn.z * rn.z * q23.x + rn.w * rn.w * q23.y;
    float bb = cn.x * cn.x * q01.x + cn.y * cn.y * q01.y + cn.z * cn.z * q23.x + cn.w * cn.w * q23.y;
    float ab = rn.x * cn.x * q01.x + rn.y * cn.y * q01.y + rn.z * cn.z * q23.x + rn.w * cn.w * q23.y;
#pragma unroll
    for (int m = 1; m < 16; m <<= 1) {
        aa += __shfl_xor(aa, m, 64);
        bb += __shfl_xor(bb, m, 64);
        ab += __shfl_xor(ab, m, 64);
    }
    if (kq == 0) {
        float na = fmaxf(sqrtf(aa), EPSV);
        float nb = fmaxf(sqrtf(bb), EPSV);
        float sim = fmaxf(ab / (na * nb), 0.0f);
        float v1 = 0.5f * L0[e] + 0.5f * sim;
        float v2 = 0.5f * L0[e + EH] + 0.5f * sim;
        vals[e] = v1;
        vals[e + EH] = v2;
        atomicAdd(&deg[row], v1);          // edge_row[e]
        atomicAdd(&deg[edge_col[e]], v2);  // edge_row[e+EH] == edge_col[e]
    }
}

__global__ void k_dinv(const float* __restrict__ deg, float* __restrict__ dinv) {
    int n = blockIdx.x * 256 + threadIdx.x;
    if (n < NNODES) {
        float d = deg[n];
        dinv[n] = d > 0.0f ? rsqrtf(d) : 0.0f;
    }
}

// ---------------- CSR aggregation + bias + relu ----------------
// half-wave (32 lanes) per node; neighbor weights precomputed lane-parallel, then
// shfl-broadcast; h gathered as fp16 (half2/lane = 128B contiguous per row).
__global__ void k_agg(const int* __restrict__ offsets, const int2* __restrict__ csr,
                      const float* __restrict__ vals, const float* __restrict__ dinv,
                      const __half* __restrict__ h, const float* __restrict__ bias,
                      float* __restrict__ xo) {
    int t = threadIdx.x;
    int n = blockIdx.x * 8 + (t >> 5);
    int sl = t & 31;
    if (n >= NNODES) return;
    float dn = dinv[n];
    int jb = offsets[n], je = offsets[n + 1];
    const __half2* h2 = (const __half2*)h;
    float2 acc = make_float2(0.0f, 0.0f);
    for (int j0 = jb; j0 < je; j0 += 32) {
        int cnt = je - j0;
        if (cnt > 32) cnt = 32;
        int col = 0;
        float wgt = 0.0f;
        if (sl < cnt) {
            int2 ce = csr[j0 + sl];
            col = ce.x;
            wgt = dn * vals[ce.y] * dinv[ce.x];
        }
        for (int u = 0; u < cnt; ++u) {
            int c = __shfl(col, u, 32);
            float wv = __shfl(wgt, u, 32);
            float2 hv = __half22float2(h2[(size_t)c * 32 + sl]);
            acc.x += wv * hv.x;
            acc.y += wv * hv.y;
        }
    }
    float2 bv = ((const float2*)bias)[sl];
    float2 o = make_float2(fmaxf(acc.x + bv.x, 0.0f), fmaxf(acc.y + bv.y, 0.0f));
    ((float2*)xo)[(size_t)n * 32 + sl] = o;
}

// ---------------- final batched dot ----------------
__global__ void k_final(const float* __restrict__ x, const int* __restrict__ uidx,
                        const int* __restrict__ iidx, const float* __restrict__ Bu,
                        const float* __restrict__ Bi, const float* __restrict__ Mu,
                        float* __restrict__ out) {
    int t = threadIdx.x;
    int le = t >> 4, kq = t & 15, k0 = kq * 4;
    int i = blockIdx.x * 16 + le;
    if (i >= NBATCH) return;
    int u = uidx[i], it = iidx[i];
    float4 a = *(const float4*)&x[(size_t)u * 64 + k0];
    float4 b = *(const float4*)&x[(size_t)(NUSERS + it) * 64 + k0];
    float d = a.x * b.x + a.y * b.y + a.z * b.z + a.w * b.w;
#pragma unroll
    for (int m = 1; m < 16; m <<= 1) d += __shfl_xor(d, m, 64);
    if (kq == 0) out[i] = d + Bu[u] + Bi[it] + Mu[0];
}

extern "C" void kernel_launch(void* const* d_in, const int* in_sizes, int n_in,
                              void* d_out, int out_size, void* d_ws, size_t ws_size,
                              hipStream_t stream) {
    const float* Gu    = (const float*)d_in[0];
    const float* Gi    = (const float*)d_in[1];
    const float* Bu    = (const float*)d_in[2];
    const float* Bi    = (const float*)d_in[3];
    const float* Mu    = (const float*)d_in[4];
    const float* projW = (const float*)d_in[5];
    const float* projb = (const float*)d_in[6];
    const float* gcnW  = (const float*)d_in[7];
    const float* gcnb  = (const float*)d_in[8];
    const float* ef    = (const float*)d_in[9];
    const float* L0    = (const float*)d_in[10];
    const int*   erow  = (const int*)d_in[11];
    const int*   ecol  = (const int*)d_in[12];
    const int*   uidx  = (const int*)d_in[13];
    const int*   iidx  = (const int*)d_in[14];
    float* out = (float*)d_out;

    char* w = (char*)d_ws;
    size_t off = 0;
    auto take = [&](size_t bytes) -> void* {
        void* p = w + off;
        off += (bytes + 255) & ~(size_t)255;
        return p;
    };
    float* x0      = (float*)take((size_t)NNODES * KDIM * 4);
    float* x1      = (float*)take((size_t)NNODES * KDIM * 4);
    __half* h      = (__half*)take((size_t)NNODES * KDIM * 2);
    float* vals    = (float*)take((size_t)E2 * 4);
    float* deg     = (float*)take((size_t)NNODES * 4);
    float* dinv    = (float*)take((size_t)NNODES * 4);
    int*   counts  = (int*)take((size_t)NPAD * 4);
    int*   offsets = (int*)take((size_t)(NNODES + 1) * 4);
    int*   cursor  = (int*)take((size_t)(NNODES + 1) * 4);
    int*   gcur    = (int*)take((size_t)NB * 4);
    int2*  csr     = (int2*)take((size_t)E2 * 8);
    __half* q      = (__half*)take((size_t)EH * KDIM * 2);
    // staging for CSR build aliases q's region (q is written after the build)
    int*  srow = (int*)q;
    int2* sce  = (int2*)((char*)q + (size_t)E2 * 4);

    // CSR build (structure is layer-invariant)
    hipMemsetAsync(counts, 0, (size_t)NPAD * 4, stream);
    k_count<<<(E2 + 255) / 256, 256, 0, stream>>>(erow, counts);
    k_scan<<<1, 1024, 0, stream>>>(counts, offsets, cursor);
    k_bcur<<<1, 128, 0, stream>>>(offsets, gcur);
    k_binA<<<256, 256, 0, stream>>>(erow, ecol, gcur, srow, sce);
    k_binB<<<NB, 512, 0, stream>>>(srow, sce, offsets, cursor, csr);

    // x0 = concat(Gu, Gi)
    hipMemcpyAsync(x0, Gu, (size_t)NUSERS * KDIM * 4, hipMemcpyDeviceToDevice, stream);
    hipMemcpyAsync(x0 + (size_t)NUSERS * KDIM, Gi, (size_t)NITEMS * KDIM * 4,
                   hipMemcpyDeviceToDevice, stream);

    // q = (ef @ projW + projb)^2 in fp16 (overwrites staging)
    k_gemm<1><<<1024, 256, 0, stream>>>(ef, projW, projb, q, EH);

    float* xc = x0;
    float* xn = x1;
    for (int l = 0; l < 3; ++l) {
        hipMemsetAsync(deg, 0, NNODES * 4, stream);
        k_sim<<<(EH + 15) / 16, 256, 0, stream>>>(xc, q, erow, ecol, L0, vals, deg);
        k_dinv<<<(NNODES + 255) / 256, 256, 0, stream>>>(deg, dinv);
        k_gemm<0><<<512, 256, 0, stream>>>(xc, gcnW + (size_t)l * 4096, nullptr, h, NNODES);
        k_agg<<<(NNODES + 7) / 8, 256, 0, stream>>>(offsets, csr, vals, dinv, h,
                                                    gcnb + (size_t)l * 64, xn);
        float* tswap = xc; xc = xn; xn = tswap;
    }
    k_final<<<(NBATCH + 15) / 16, 256, 0, stream>>>(xc, uidx, iidx, Bu, Bi, Mu, out);
}

// Round 4
// 897.837 us; speedup vs baseline: 2.0634x; 1.0965x over previous
//
#include <hip/hip_runtime.h>
#include <hip/hip_fp16.h>

#define NUSERS 60000
#define NITEMS 30000
#define NNODES 90000
#define KDIM 64
#define EH 1000000
#define E2 2000000
#define NBATCH 100000
#define EPSV 1e-8f

#define NB 128      // coarse buckets for CSR builds
#define RPB_I 240   // 128*240 = 30720 >= NITEMS
#define RPB_U 472   // 128*472 = 60416 >= NUSERS
#define CHUNK 2048  // edges per block-round in binA
#define NPAD_I 32768
#define NPAD_U 61440

typedef __attribute__((ext_vector_type(8))) short short8v;
typedef __attribute__((ext_vector_type(4))) float f32x4;

__device__ inline float4 h4_to_f4(const __half* p) {
    float2 raw = *(const float2*)p;  // single 8B load
    __half2 a = *(__half2*)&raw.x;
    __half2 b = *(__half2*)&raw.y;
    float2 fa = __half22float2(a), fb = __half22float2(b);
    return make_float4(fa.x, fa.y, fb.x, fb.y);
}

// ---------------- CSR builds ----------------
__global__ void k_count2(const int* __restrict__ erow, const int* __restrict__ ecol,
                         int* __restrict__ cntI, int* __restrict__ cntU) {
    int e = blockIdx.x * 256 + threadIdx.x;
    if (e < EH) {
        atomicAdd(&cntI[erow[e] - NUSERS], 1);
        atomicAdd(&cntU[ecol[e]], 1);
    }
}

// grid=2: block 0 scans item counts, block 1 user counts (concurrent)
__global__ void k_scan2(const int* __restrict__ cntI, int* __restrict__ ofsI,
                        int* __restrict__ curI, const int* __restrict__ cntU,
                        int* __restrict__ ofsU, int* __restrict__ curU) {
    const int* counts; int* offsets; int* cursor; int n;
    if (blockIdx.x == 0) { counts = cntI; offsets = ofsI; cursor = curI; n = NITEMS; }
    else                 { counts = cntU; offsets = ofsU; cursor = curU; n = NUSERS; }
    __shared__ int wsum[17];
    int t = threadIdx.x;
    int lane = t & 63, wid = t >> 6;
    int carry = 0;
    int npad = (n + 4095) & ~4095;
    for (int base = 0; base < npad; base += 4096) {
        int i0 = base + t * 4;
        int4 v = *(const int4*)&counts[i0];  // padded+zeroed, safe
        int s0 = v.x, s1 = s0 + v.y, s2 = s1 + v.z, s3 = s2 + v.w;
        int ws = s3;
#pragma unroll
        for (int o = 1; o < 64; o <<= 1) {
            int u = __shfl_up(ws, o, 64);
            if (lane >= o) ws += u;
        }
        if (lane == 63) wsum[wid] = ws;
        __syncthreads();
        if (wid == 0) {
            int wv = (lane < 16) ? wsum[lane] : 0;
#pragma unroll
            for (int o = 1; o < 16; o <<= 1) {
                int u = __shfl_up(wv, o, 64);
                if (lane >= o) wv += u;
            }
            if (lane < 16) wsum[lane] = wv;
            if (lane == 15) wsum[16] = wv;
        }
        __syncthreads();
        int wbase = (wid > 0) ? wsum[wid - 1] : 0;
        int texcl = carry + wbase + (ws - s3);
        if (i0 < n)     { offsets[i0]     = texcl;      cursor[i0]     = texcl; }
        if (i0 + 1 < n) { offsets[i0 + 1] = texcl + s0; cursor[i0 + 1] = texcl + s0; }
        if (i0 + 2 < n) { offsets[i0 + 2] = texcl + s1; cursor[i0 + 2] = texcl + s1; }
        if (i0 + 3 < n) { offsets[i0 + 3] = texcl + s2; cursor[i0 + 3] = texcl + s2; }
        carry += wsum[16];
        __syncthreads();
    }
    if (t == 0) offsets[n] = carry;
}

__global__ void k_bcur2(const int* __restrict__ ofsI, const int* __restrict__ ofsU,
                        int* __restrict__ gcurI, int* __restrict__ gcurU) {
    int t = threadIdx.x;
    if (t < NB) {
        int rI = t * RPB_I; if (rI > NITEMS) rI = NITEMS;
        int rU = t * RPB_U; if (rU > NUSERS) rU = NUSERS;
        gcurI[t] = ofsI[rI];
        gcurU[t] = ofsU[rU];
    }
}

// Pass A: LDS counting-sort into NB buckets, coalesced append into bucket regions.
// PHASE 0 (item CSR): row = erow[e]-NUSERS, payload {ecol[e], e}
// PHASE 1 (user CSR): row = ecol[e],        payload {erow[e], inv[e]}
template <int PHASE, int RPBX>
__global__ void k_binA(const int* __restrict__ erow, const int* __restrict__ ecol,
                       const int* __restrict__ inv, int* __restrict__ gcur,
                       int* __restrict__ srow, int2* __restrict__ spay) {
    __shared__ int bcnt[NB];
    __shared__ int bbase[NB];
    __shared__ int bpos[NB];
    __shared__ int bglob[NB];
    __shared__ int wtot[2];
    __shared__ int lrow[CHUNK];
    __shared__ int2 lce[CHUNK];
    int t = threadIdx.x;
    for (int base = blockIdx.x * CHUNK; base < EH; base += gridDim.x * CHUNK) {
        for (int i = t; i < NB; i += 256) bcnt[i] = 0;
        __syncthreads();
        int mr[8], mx[8], my[8], mb[8];
#pragma unroll
        for (int k = 0; k < 8; ++k) {
            int e = base + k * 256 + t;
            if (e < EH) {
                int r, px, py;
                if (PHASE == 0) { r = erow[e] - NUSERS; px = ecol[e]; py = e; }
                else            { r = ecol[e];          px = erow[e]; py = inv[e]; }
                mr[k] = r; mx[k] = px; my[k] = py;
                mb[k] = r / RPBX;
                atomicAdd(&bcnt[mb[k]], 1);
            } else {
                mb[k] = -1;
            }
        }
        __syncthreads();
        if (t < NB) {
            int v = bcnt[t];
            int s = v;
#pragma unroll
            for (int o = 1; o < 64; o <<= 1) {
                int u = __shfl_up(s, o, 64);
                if ((t & 63) >= o) s += u;
            }
            bbase[t] = s - v;
            if ((t & 63) == 63) wtot[t >> 6] = s;
        }
        __syncthreads();
        if (t >= 64 && t < NB) bbase[t] += wtot[0];
        if (t < NB) bpos[t] = 0;
        __syncthreads();
#pragma unroll
        for (int k = 0; k < 8; ++k) {
            if (mb[k] >= 0) {
                int p = bbase[mb[k]] + atomicAdd(&bpos[mb[k]], 1);
                lrow[p] = mr[k];
                lce[p] = make_int2(mx[k], my[k]);
            }
        }
        __syncthreads();
        if (t < NB) bglob[t] = bcnt[t] ? atomicAdd(&gcur[t], bcnt[t]) : 0;
        __syncthreads();
        int total = bbase[NB - 1] + bcnt[NB - 1];
        for (int i = t; i < total; i += 256) {
            int r = lrow[i];
            int b = r / RPBX;
            int dest = bglob[b] + (i - bbase[b]);
            srow[dest] = r;
            spay[dest] = lce[i];
        }
        __syncthreads();
    }
}

// Pass B (item CSR): scatter within L2-resident bucket window; slot-renumber edge data.
__global__ void k_binB0(const int* __restrict__ srow, const int2* __restrict__ spay,
                        const int* __restrict__ ofsI, int* __restrict__ curI,
                        const float* __restrict__ L0, int* __restrict__ colp,
                        int* __restrict__ eorig, int* __restrict__ inv,
                        float2* __restrict__ L0p) {
    int b = blockIdx.x;
    int r0 = b * RPB_I; if (r0 > NITEMS) r0 = NITEMS;
    int r1 = (b + 1) * RPB_I; if (r1 > NITEMS) r1 = NITEMS;
    int lo = ofsI[r0], hi = ofsI[r1];
    for (int i = lo + threadIdx.x; i < hi; i += blockDim.x) {
        int r = srow[i];
        int2 p = spay[i];  // {user, e}
        int slot = atomicAdd(&curI[r], 1);
        colp[slot] = p.x;
        eorig[slot] = p.y;
        inv[p.y] = slot;
        L0p[slot] = make_float2(L0[p.y], L0[p.y + EH]);
    }
}

// Pass B (user CSR): entries {item_global, slot}
__global__ void k_binB1(const int* __restrict__ srow, const int2* __restrict__ spay,
                        const int* __restrict__ ofsU, int* __restrict__ curU,
                        int2* __restrict__ csrU) {
    int b = blockIdx.x;
    int r0 = b * RPB_U; if (r0 > NUSERS) r0 = NUSERS;
    int r1 = (b + 1) * RPB_U; if (r1 > NUSERS) r1 = NUSERS;
    int lo = ofsU[r0], hi = ofsU[r1];
    for (int i = lo + threadIdx.x; i < hi; i += blockDim.x) {
        int r = srow[i];
        int2 p = spay[i];
        int slot = atomicAdd(&curU[r], 1);
        csrU[slot] = p;
    }
}

// ---------------- MFMA 64-col GEMM ----------------
// MODE 1: qp[slot] = (ef[eorig[slot]]@W + b)^2, fp16 out (gathered A rows).
// MODE 0: h = x@W fp16 out; also xh = fp16(x).
template <int MODE>
__global__ void k_gemm(const float* __restrict__ A, const float* __restrict__ W,
                       const float* __restrict__ bias, void* __restrict__ out, int M,
                       const int* __restrict__ eorig, __half* __restrict__ xh) {
    __shared__ float Ws[4096];
    int t = threadIdx.x;
    for (int i = t; i < 4096; i += 256) Ws[i] = W[i];
    __syncthreads();
    int lane = t & 63;
    int wid = t >> 6;
    int lr = lane & 15;
    int kg = lane >> 4;
    short8v Bh[2][4], Bl[2][4];
#pragma unroll
    for (int kt = 0; kt < 2; ++kt)
#pragma unroll
        for (int ct = 0; ct < 4; ++ct) {
            short8v bh, bl;
#pragma unroll
            for (int i = 0; i < 8; ++i) {
                int k = kt * 32 + kg * 8 + i;
                float v = Ws[k * 64 + ct * 16 + lr];
                unsigned u = __float_as_uint(v);
                float d = v - __uint_as_float(u & 0xffff0000u);
                bh[i] = (short)(u >> 16);
                bl[i] = (short)(__float_as_uint(d) >> 16);
            }
            Bh[kt][ct] = bh;
            Bl[kt][ct] = bl;
        }
    float bcol[4];
    if (MODE == 1) {
#pragma unroll
        for (int ct = 0; ct < 4; ++ct) bcol[ct] = bias[ct * 16 + lr];
    }
    int nt = M >> 4;
    int nw = gridDim.x * 4;
    for (int tile = blockIdx.x * 4 + wid; tile < nt; tile += nw) {
        int r0 = tile << 4;
        int arow = (MODE == 1) ? eorig[r0 + lr] : (r0 + lr);
        const float* ap = &A[(size_t)arow * 64 + kg * 8];
        float4 a0 = *(const float4*)ap;
        float4 a1 = *(const float4*)(ap + 4);
        float4 a2 = *(const float4*)(ap + 32);
        float4 a3 = *(const float4*)(ap + 36);
        float av[16] = {a0.x, a0.y, a0.z, a0.w, a1.x, a1.y, a1.z, a1.w,
                        a2.x, a2.y, a2.z, a2.w, a3.x, a3.y, a3.z, a3.w};
        if (MODE == 0) {  // emit xh = fp16(x): cols kg*8..+7 and 32+kg*8..+7
            short8v pk0, pk1;
#pragma unroll
            for (int i = 0; i < 8; ++i) {
                pk0[i] = __half_as_short(__float2half(av[i]));
                pk1[i] = __half_as_short(__float2half(av[8 + i]));
            }
            *(short8v*)&xh[(size_t)(r0 + lr) * 64 + kg * 8] = pk0;
            *(short8v*)&xh[(size_t)(r0 + lr) * 64 + 32 + kg * 8] = pk1;
        }
        short8v Ah[2], Al[2];
#pragma unroll
        for (int kt = 0; kt < 2; ++kt) {
            short8v ah, al;
#pragma unroll
            for (int i = 0; i < 8; ++i) {
                float v = av[kt * 8 + i];
                unsigned u = __float_as_uint(v);
                float d = v - __uint_as_float(u & 0xffff0000u);
                ah[i] = (short)(u >> 16);
                al[i] = (short)(__float_as_uint(d) >> 16);
            }
            Ah[kt] = ah;
            Al[kt] = al;
        }
        f32x4 acc[4] = {{0, 0, 0, 0}, {0, 0, 0, 0}, {0, 0, 0, 0}, {0, 0, 0, 0}};
#pragma unroll
        for (int kt = 0; kt < 2; ++kt)
#pragma unroll
            for (int ct = 0; ct < 4; ++ct) {
                acc[ct] = __builtin_amdgcn_mfma_f32_16x16x32_bf16(Ah[kt], Bh[kt][ct], acc[ct], 0, 0, 0);
                acc[ct] = __builtin_amdgcn_mfma_f32_16x16x32_bf16(Al[kt], Bh[kt][ct], acc[ct], 0, 0, 0);
                acc[ct] = __builtin_amdgcn_mfma_f32_16x16x32_bf16(Ah[kt], Bl[kt][ct], acc[ct], 0, 0, 0);
            }
        // D layout (m89-verified): col = ct*16 + (lane&15), row = r0 + (lane>>4)*4 + r
#pragma unroll
        for (int ct = 0; ct < 4; ++ct)
#pragma unroll
            for (int r = 0; r < 4; ++r) {
                int row = r0 + kg * 4 + r;
                int col = ct * 16 + lr;
                float p = acc[ct][r];
                if (MODE == 1) {
                    p += bcol[ct];
                    ((__half*)out)[(size_t)row * 64 + col] = __float2half(p * p);
                } else {
                    ((__half*)out)[(size_t)row * 64 + col] = __float2half(p);
                }
            }
    }
}

// ---------------- per-edge similarity, item-CSR order ----------------
// wave per item: rn loaded once; 4 edges/iteration via 16-lane groups.
// All per-edge arrays (colp, qp, L0p, v1p, v2p) stream sequentially.
__global__ void __launch_bounds__(256) k_sim(
        const __half* __restrict__ xh, const __half* __restrict__ qp,
        const int* __restrict__ colp, const float2* __restrict__ L0p,
        const int* __restrict__ ofsI, float* __restrict__ v1p,
        float* __restrict__ v2p, float* __restrict__ deg) {
    int t = threadIdx.x;
    int wid = t >> 6, lane = t & 63, g = lane >> 4, kq = lane & 15;
    int item = blockIdx.x * 4 + wid;
    if (item >= NITEMS) return;
    float4 rn = h4_to_f4(&xh[(size_t)(NUSERS + item) * 64 + kq * 4]);
    int jb = ofsI[item], je = ofsI[item + 1];
    float dacc = 0.0f;
    for (int j0 = jb; j0 < je; j0 += 4) {
        int j = j0 + g;
        bool act = j < je;
        int user = 0;
        float4 cn = make_float4(0, 0, 0, 0), qv = make_float4(0, 0, 0, 0);
        if (act) {
            user = colp[j];
            cn = h4_to_f4(&xh[(size_t)user * 64 + kq * 4]);
            qv = h4_to_f4(&qp[(size_t)j * 64 + kq * 4]);
        }
        float aa = rn.x * rn.x * qv.x + rn.y * rn.y * qv.y + rn.z * rn.z * qv.z + rn.w * rn.w * qv.w;
        float bb = cn.x * cn.x * qv.x + cn.y * cn.y * qv.y + cn.z * cn.z * qv.z + cn.w * cn.w * qv.w;
        float ab = rn.x * cn.x * qv.x + rn.y * cn.y * qv.y + rn.z * cn.z * qv.z + rn.w * cn.w * qv.w;
#pragma unroll
        for (int m = 1; m < 16; m <<= 1) {
            aa += __shfl_xor(aa, m, 64);
            bb += __shfl_xor(bb, m, 64);
            ab += __shfl_xor(ab, m, 64);
        }
        if (kq == 0 && act) {
            float na = fmaxf(sqrtf(aa), EPSV);
            float nb = fmaxf(sqrtf(bb), EPSV);
            float sim = fmaxf(ab / (na * nb), 0.0f);
            float2 l0 = L0p[j];
            float v1 = 0.5f * l0.x + 0.5f * sim;
            float v2 = 0.5f * l0.y + 0.5f * sim;
            v1p[j] = v1;
            v2p[j] = v2;
            atomicAdd(&deg[user], v2);
            dacc += v1;
        }
    }
    dacc += __shfl_xor(dacc, 16, 64);
    dacc += __shfl_xor(dacc, 32, 64);
    if (lane == 0) deg[NUSERS + item] = dacc;  // exclusive: plain store
}

__global__ void k_dinv(const float* __restrict__ deg, float* __restrict__ dinv) {
    int n = blockIdx.x * 256 + threadIdx.x;
    if (n < NNODES) {
        float d = deg[n];
        dinv[n] = d > 0.0f ? rsqrtf(d) : 0.0f;
    }
}

// ---------------- aggregation + bias + relu ----------------
// blocks [0, 3750): item rows via item-CSR (colp/v1p streaming)
// blocks [3750, 11250): user rows via user-CSR (csrU streaming, v2p gathered)
#define IBLK 3750
__global__ void __launch_bounds__(256) k_agg(
        const int* __restrict__ ofsI, const int* __restrict__ colp,
        const float* __restrict__ v1p, const int* __restrict__ ofsU,
        const int2* __restrict__ csrU, const float* __restrict__ v2p,
        const float* __restrict__ dinv, const __half* __restrict__ h,
        const float* __restrict__ bias, float* __restrict__ xo) {
    int t = threadIdx.x;
    int half_id = t >> 5, sl = t & 31;
    const __half2* h2 = (const __half2*)h;
    float2 bv = ((const float2*)bias)[sl];
    float2 acc = make_float2(0.0f, 0.0f);
    int node;
    if (blockIdx.x < IBLK) {
        int il = blockIdx.x * 8 + half_id;  // 0..29999
        node = NUSERS + il;
        float dn = dinv[node];
        int jb = ofsI[il], je = ofsI[il + 1];
        for (int j0 = jb; j0 < je; j0 += 32) {
            int cnt = je - j0;
            if (cnt > 32) cnt = 32;
            int col = 0;
            float wgt = 0.0f;
            if (sl < cnt) {
                col = colp[j0 + sl];
                wgt = dn * v1p[j0 + sl] * dinv[col];
            }
            for (int u = 0; u < cnt; ++u) {
                int c = __shfl(col, u, 32);
                float wv = __shfl(wgt, u, 32);
                float2 hv = __half22float2(h2[(size_t)c * 32 + sl]);
                acc.x += wv * hv.x;
                acc.y += wv * hv.y;
            }
        }
    } else {
        int ul = (blockIdx.x - IBLK) * 8 + half_id;  // 0..59999
        node = ul;
        float dn = dinv[ul];
        int jb = ofsU[ul], je = ofsU[ul + 1];
        for (int j0 = jb; j0 < je; j0 += 32) {
            int cnt = je - j0;
            if (cnt > 32) cnt = 32;
            int col = 0;
            float wgt = 0.0f;
            if (sl < cnt) {
                int2 ce = csrU[j0 + sl];
                col = ce.x;
                wgt = dn * v2p[ce.y] * dinv[col];
            }
            for (int u = 0; u < cnt; ++u) {
                int c = __shfl(col, u, 32);
                float wv = __shfl(wgt, u, 32);
                float2 hv = __half22float2(h2[(size_t)c * 32 + sl]);
                acc.x += wv * hv.x;
                acc.y += wv * hv.y;
            }
        }
    }
    float2 o = make_float2(fmaxf(acc.x + bv.x, 0.0f), fmaxf(acc.y + bv.y, 0.0f));
    ((float2*)xo)[(size_t)node * 32 + sl] = o;
}

// ---------------- final batched dot ----------------
__global__ void k_final(const float* __restrict__ x, const int* __restrict__ uidx,
                        const int* __restrict__ iidx, const float* __restrict__ Bu,
                        const float* __restrict__ Bi, const float* __restrict__ Mu,
                        float* __restrict__ out) {
    int t = threadIdx.x;
    int le = t >> 4, kq = t & 15, k0 = kq * 4;
    int i = blockIdx.x * 16 + le;
    if (i >= NBATCH) return;
    int u = uidx[i], it = iidx[i];
    float4 a = *(const float4*)&x[(size_t)u * 64 + k0];
    float4 b = *(const float4*)&x[(size_t)(NUSERS + it) * 64 + k0];
    float d = a.x * b.x + a.y * b.y + a.z * b.z + a.w * b.w;
#pragma unroll
    for (int m = 1; m < 16; m <<= 1) d += __shfl_xor(d, m, 64);
    if (kq == 0) out[i] = d + Bu[u] + Bi[it] + Mu[0];
}

extern "C" void kernel_launch(void* const* d_in, const int* in_sizes, int n_in,
                              void* d_out, int out_size, void* d_ws, size_t ws_size,
                              hipStream_t stream) {
    const float* Gu    = (const float*)d_in[0];
    const float* Gi    = (const float*)d_in[1];
    const float* Bu    = (const float*)d_in[2];
    const float* Bi    = (const float*)d_in[3];
    const float* Mu    = (const float*)d_in[4];
    const float* projW = (const float*)d_in[5];
    const float* projb = (const float*)d_in[6];
    const float* gcnW  = (const float*)d_in[7];
    const float* gcnb  = (const float*)d_in[8];
    const float* ef    = (const float*)d_in[9];
    const float* L0    = (const float*)d_in[10];
    const int*   erow  = (const int*)d_in[11];
    const int*   ecol  = (const int*)d_in[12];
    const int*   uidx  = (const int*)d_in[13];
    const int*   iidx  = (const int*)d_in[14];
    float* out = (float*)d_out;

    char* w = (char*)d_ws;
    size_t off = 0;
    auto take = [&](size_t bytes) -> void* {
        void* p = w + off;
        off += (bytes + 255) & ~(size_t)255;
        return p;
    };
    float*  x0    = (float*)take((size_t)NNODES * KDIM * 4);
    float*  x1    = (float*)take((size_t)NNODES * KDIM * 4);
    __half* h     = (__half*)take((size_t)NNODES * KDIM * 2);
    __half* xh    = (__half*)take((size_t)NNODES * KDIM * 2);
    float*  v1p   = (float*)take((size_t)EH * 4);
    float*  v2p   = (float*)take((size_t)EH * 4);
    float*  deg   = (float*)take((size_t)NNODES * 4);
    float*  dinv  = (float*)take((size_t)NNODES * 4);
    int*    cntI  = (int*)take((size_t)NPAD_I * 4);   // adjacent with cntU: one memset
    int*    cntU  = (int*)take((size_t)NPAD_U * 4);
    int*    ofsI  = (int*)take((size_t)(NITEMS + 1) * 4);
    int*    curI  = (int*)take((size_t)(NITEMS + 1) * 4);
    int*    ofsU  = (int*)take((size_t)(NUSERS + 1) * 4);
    int*    curU  = (int*)take((size_t)(NUSERS + 1) * 4);
    int*    gcurI = (int*)take((size_t)NB * 4);
    int*    gcurU = (int*)take((size_t)NB * 4);
    int*    colp  = (int*)take((size_t)EH * 4);
    int*    eorig = (int*)take((size_t)EH * 4);
    int*    inv   = (int*)take((size_t)EH * 4);
    float2* L0p   = (float2*)take((size_t)EH * 8);
    int2*   csrU  = (int2*)take((size_t)EH * 8);
    __half* qp    = (__half*)take((size_t)EH * KDIM * 2);
    // CSR-build staging aliases qp (qp written only after both builds)
    int*  srow = (int*)qp;
    int2* spay = (int2*)((char*)qp + (size_t)EH * 4);

    // ---- CSR builds (layer-invariant) ----
    hipMemsetAsync(cntI, 0, (size_t)(NPAD_I + NPAD_U) * 4, stream);
    k_count2<<<(EH + 255) / 256, 256, 0, stream>>>(erow, ecol, cntI, cntU);
    k_scan2<<<2, 1024, 0, stream>>>(cntI, ofsI, curI, cntU, ofsU, curU);
    k_bcur2<<<1, 128, 0, stream>>>(ofsI, ofsU, gcurI, gcurU);
    k_binA<0, RPB_I><<<256, 256, 0, stream>>>(erow, ecol, nullptr, gcurI, srow, spay);
    k_binB0<<<NB, 512, 0, stream>>>(srow, spay, ofsI, curI, L0, colp, eorig, inv, L0p);
    k_binA<1, RPB_U><<<256, 256, 0, stream>>>(erow, ecol, inv, gcurU, srow, spay);
    k_binB1<<<NB, 512, 0, stream>>>(srow, spay, ofsU, curU, csrU);

    // qp[slot] = (ef[eorig[slot]] @ projW + projb)^2, fp16 (overwrites staging)
    k_gemm<1><<<1024, 256, 0, stream>>>(ef, projW, projb, qp, EH, eorig, nullptr);

    // x0 = concat(Gu, Gi)
    hipMemcpyAsync(x0, Gu, (size_t)NUSERS * KDIM * 4, hipMemcpyDeviceToDevice, stream);
    hipMemcpyAsync(x0 + (size_t)NUSERS * KDIM, Gi, (size_t)NITEMS * KDIM * 4,
                   hipMemcpyDeviceToDevice, stream);

    float* xc = x0;
    float* xn = x1;
    for (int l = 0; l < 3; ++l) {
        k_gemm<0><<<512, 256, 0, stream>>>(xc, gcnW + (size_t)l * 4096, nullptr, h,
                                           NNODES, nullptr, xh);
        hipMemsetAsync(deg, 0, (size_t)NUSERS * 4, stream);  // item half plain-stored
        k_sim<<<(NITEMS + 3) / 4, 256, 0, stream>>>(xh, qp, colp, L0p, ofsI, v1p, v2p, deg);
        k_dinv<<<(NNODES + 255) / 256, 256, 0, stream>>>(deg, dinv);
        k_agg<<<IBLK + NUSERS / 8, 256, 0, stream>>>(ofsI, colp, v1p, ofsU, csrU, v2p,
                                                     dinv, h, gcnb + (size_t)l * 64, xn);
        float* tswap = xc; xc = xn; xn = tswap;
    }
    k_final<<<(NBATCH + 15) / 16, 256, 0, stream>>>(xc, uidx, iidx, Bu, Bi, Mu, out);
}